// Round 2
// baseline (167.642 us; speedup 1.0000x reference)
//
#include <hip/hip_runtime.h>

// MHSA fused pipeline v8, MI355X gfx950.
// B=2, N=2048, C=1024, H=16, dim=64.
//
// v8 (from v7): address diet. v7 showed bank-conflict elimination (4.26M->0)
// and MFMA/VALU reorder are both NULL -> critical path is VALU issue + stalls,
// and the VALU bulk is per-iter address recomputation, not exp2/pack.
// Changes: (1) K-loop hand-unrolled x2 so `cur` is compile-time; all LDS reads
// go through 4 precomputed per-lane pointers kp[ks] with mt/V/dt/buffer folded
// into ds_read offset immediates (swzr(row+32)==swzr(row) makes deltas
// constant: mt +4096B, V +8192B, dt +4096B, buf +16384B). (2) Staging uses 4
// running global pointers incremented by constants. (3) v7's dual-live-St
// reorder reverted (measured null; frees ~16 regs to pay for pointers, keeps
// total regs <=128 -> 16 waves/CU). (4) T5 s_setprio(1) around MFMA clusters.

#define H 16
#define NSEQ 2048
#define CCH 1024
#define BATCH 2
#define DSTR (H * NSEQ)  // 32768

typedef __attribute__((ext_vector_type(8))) short bf16x8;
typedef __attribute__((ext_vector_type(2))) float f32x2;
typedef __attribute__((ext_vector_type(4))) float f32x4;
typedef __attribute__((ext_vector_type(16))) float f32x16;
typedef __attribute__((ext_vector_type(4))) unsigned int uint32x4;

__device__ __forceinline__ unsigned short f2bf(float x) {
  unsigned int u = __builtin_bit_cast(unsigned int, x);
  u += 0x7FFFu + ((u >> 16) & 1u);  // RNE
  return (unsigned short)(u >> 16);
}

__device__ __forceinline__ unsigned int pack2bf(float a, float b) {
#if __has_builtin(__builtin_amdgcn_cvt_pk_bf16_f32)
  typedef __attribute__((ext_vector_type(2))) __bf16 bf16x2_t;
  bf16x2_t r = __builtin_amdgcn_cvt_pk_bf16_f32(a, b);
  return __builtin_bit_cast(unsigned int, r);
#else
  unsigned int ua = __builtin_bit_cast(unsigned int, a);
  unsigned int ub = __builtin_bit_cast(unsigned int, b);
  ua += 0x7FFFu + ((ua >> 16) & 1u);
  ub += 0x7FFFu + ((ub >> 16) & 1u);
  return __builtin_amdgcn_perm(ub, ua, 0x07060302u);
#endif
}

__device__ __forceinline__ float fast_exp2(float x) {
#if __has_builtin(__builtin_amdgcn_exp2f)
  return __builtin_amdgcn_exp2f(x);
#else
  return exp2f(x);
#endif
}

__device__ __forceinline__ void permswap32(unsigned int& a, unsigned int& b) {
#if __has_builtin(__builtin_amdgcn_permlane32_swap)
  typedef __attribute__((ext_vector_type(2))) unsigned int uint2v;
  uint2v r = __builtin_amdgcn_permlane32_swap(a, b, false, false);
  a = r[0];
  b = r[1];
#else
  unsigned int ax = (unsigned int)__shfl_xor((int)a, 32, 64);
  unsigned int bx = (unsigned int)__shfl_xor((int)b, 32, 64);
  bool lo = (threadIdx.x & 63) < 32;
  unsigned int na = lo ? a : bx;
  unsigned int nb = lo ? ax : b;
  a = na;
  b = nb;
#endif
}

__device__ __forceinline__ void gld16(const void* g, void* l) {
  __builtin_amdgcn_global_load_lds(
      (const __attribute__((address_space(1))) unsigned int*)g,
      (__attribute__((address_space(3))) unsigned int*)l, 16, 0, 0);
}

__device__ __forceinline__ f32x16 zero16() {
  f32x16 v;
#pragma unroll
  for (int i = 0; i < 16; ++i) v[i] = 0.f;
  return v;
}

// XOR swizzle, self-inverse, period 32 in row: swzr(row+32) == swzr(row).
__device__ __forceinline__ int swzr(int row) { return (row & 7) ^ ((row >> 3) & 3); }

// ---------------- fused prep: W permute | V convert | Q/K transpose ----------------
__global__ __launch_bounds__(256) void prep_all(const float* __restrict__ W,
                                                const float* __restrict__ v,
                                                const float* __restrict__ q,
                                                const float* __restrict__ k,
                                                unsigned short* __restrict__ Wp,
                                                unsigned short* __restrict__ Vb,
                                                unsigned short* __restrict__ Qt,
                                                unsigned short* __restrict__ Kt) {
  __shared__ unsigned short T[64][72];
  const int bid = blockIdx.x, tid = threadIdx.x;

  if (bid < 1024) {
    const int o = bid;
    const int cp = tid * 4;
    const int hh = cp >> 6;
    const int d0 = cp & 63;
    const float* Wr = W + (size_t)o * CCH;
    ushort4 ov;
    ov.x = f2bf(Wr[(d0 + 0) * H + hh]);
    ov.y = f2bf(Wr[(d0 + 1) * H + hh]);
    ov.z = f2bf(Wr[(d0 + 2) * H + hh]);
    ov.w = f2bf(Wr[(d0 + 3) * H + hh]);
    *(ushort4*)&Wp[(size_t)o * CCH + cp] = ov;
  } else if (bid < 5120) {
    int idx = (bid - 1024) * 256 + tid;
    float4 x = ((const float4*)v)[idx];
    ushort4 o;
    o.x = f2bf(x.x); o.y = f2bf(x.y); o.z = f2bf(x.z); o.w = f2bf(x.w);
    ((ushort4*)Vb)[idx] = o;
  } else {
    const int lbid = bid - 5120;
    const int n0 = (lbid & 31) * 64;
    const int hh = (lbid >> 5) & 15;
    const int zz = lbid >> 9;
    const int b = zz >> 1, t = zz & 1;
    const float* src = t ? k : q;
    unsigned short* dst = t ? Kt : Qt;
    // Q scale: 1/sqrt(2048) * log2(e)  (softmax exp -> exp2)
    const float scl = t ? 1.0f : (0.022097086912079608f * 1.4426950408889634f);
    const size_t base = (size_t)b * (CCH * NSEQ) + (size_t)hh * NSEQ;
#pragma unroll
    for (int it = 0; it < 4; ++it) {
      int i4 = it * 256 + tid;
      int d = i4 >> 4;
      int nn = (i4 & 15) << 2;
      float4 val = *(const float4*)(src + base + (size_t)d * DSTR + n0 + nn);
      T[nn + 0][d] = f2bf(val.x * scl);
      T[nn + 1][d] = f2bf(val.y * scl);
      T[nn + 2][d] = f2bf(val.z * scl);
      T[nn + 3][d] = f2bf(val.w * scl);
    }
    __syncthreads();
    const size_t obase = ((size_t)(b * H + hh) * NSEQ + n0) * 64;
#pragma unroll
    for (int it = 0; it < 2; ++it) {
      int idx = it * 256 + tid;
      int row = idx >> 3, cb = idx & 7;
      *(bf16x8*)(dst + obase + (size_t)row * 64 + cb * 8) = *(const bf16x8*)&T[row][cb * 8];
    }
  }
}

// ---- attn helpers ----

// QK^T 32x32 tile: 4 MFMAs via precomputed per-lane pointers + const offset.
__device__ __forceinline__ f32x16 qk4(const char* const* kp, int off, const bf16x8* bQ) {
  f32x16 St = zero16();
#pragma unroll
  for (int ks = 0; ks < 4; ++ks) {
    bf16x8 aK = *(const bf16x8*)(kp[ks] + off);
    St = __builtin_amdgcn_mfma_f32_32x32x16_bf16(aK, bQ[ks], St, 0, 0, 0);
  }
  return St;
}

// P = exp2(St), pack to bf16, C-layout -> A-layout in-register.
__device__ __forceinline__ void exppack(const f32x16& St, f32x2& ls2, bf16x8& a0, bf16x8& a1) {
  unsigned int pd[8];
#pragma unroll
  for (int t = 0; t < 8; ++t) {
    float e0 = fast_exp2(St[2 * t]);
    float e1 = fast_exp2(St[2 * t + 1]);
    ls2 += (f32x2){e0, e1};
    pd[t] = pack2bf(e0, e1);
  }
  unsigned int s0[4] = {pd[0], pd[1], pd[2], pd[3]};
  unsigned int s1[4] = {pd[4], pd[5], pd[6], pd[7]};
  permswap32(s0[0], s0[2]);
  permswap32(s0[1], s0[3]);
  permswap32(s1[0], s1[2]);
  permswap32(s1[1], s1[3]);
  a0 = __builtin_bit_cast(bf16x8, (uint32x4){s0[0], s0[1], s0[2], s0[3]});
  a1 = __builtin_bit_cast(bf16x8, (uint32x4){s1[0], s1[1], s1[2], s1[3]});
}

// ---------------- attention v8 ----------------
// grid (16,16,2) = 512 blocks (2/CU), block 512 = 8 waves: g = m-group (2 x 1024 m),
// nw = n-wave (4 x 32 rows). 16 waves/CU resident.
__global__ __launch_bounds__(512, 4) void attn8(const unsigned short* __restrict__ Qt,
                                                const unsigned short* __restrict__ Kt,
                                                const unsigned short* __restrict__ Vb,
                                                unsigned short* __restrict__ xt) {
  // 64 KB K/V tiles ([g][buf][kv] x 8 KB) + 1 KB lsum; epilogue reuses KV
  // area as Oex[128][64] f32 (32 KB).
  __shared__ __align__(16) unsigned char sbuf[65536 + 1024];
  unsigned short* KV = (unsigned short*)sbuf;
  float* lsumLDS = (float*)(sbuf + 65536);  // [2][128]
  float* Oex = (float*)sbuf;                // [128][64]

  const int tid = threadIdx.x;
  const int w = tid >> 6, lane = tid & 63;
  const int lane31 = lane & 31, hl = lane >> 5;
  const int g = w >> 2, nw = w & 3;
  const int n0 = blockIdx.x * 128;
  const int hh = blockIdx.y, b = blockIdx.z;

  const unsigned short* Qbase = Qt + ((size_t)(b * H + hh) * NSEQ + n0) * 64;
  const unsigned short* Kg = Kt + ((size_t)(b * H + hh) * NSEQ + g * 1024) * 64;
  const unsigned short* Vg = Vb + (size_t)b * (CCH * NSEQ) + (size_t)hh * NSEQ + g * 1024;

  const int r8 = lane >> 3, scb = lane & 7;

#define KVOFF(gg, bb, kk) ((((gg)*2 + (bb)) * 2 + (kk)) * 4096)

  // ---- stage Q (128x64 = 16 KB, swizzled) into the KV area, all 8 waves ----
#pragma unroll
  for (int i = 0; i < 2; ++i) {
    int row = i * 64 + w * 8 + r8;
    int cbl = scb ^ swzr(row);
    gld16(Qbase + (size_t)row * 64 + cbl * 8, KV + (i * 64 + w * 8) * 64);
  }
  __syncthreads();

  // ---- loop-invariant Q B-fragments: B[col=n=lane31][k=d] ----
  bf16x8 bQ[4];
#pragma unroll
  for (int ks = 0; ks < 4; ++ks) {
    int row = nw * 32 + lane31;
    int phys = (ks * 2 + hl) ^ swzr(row);
    bQ[ks] = *(const bf16x8*)(KV + (size_t)row * 64 + phys * 8);
  }
  __syncthreads();  // Q reads done; KV becomes K/V tile space

  // ---- precomputed per-lane LDS read pointers ----
  // K read (mt, ks, cur): kp[ks] + mt*4096 + cur*16384
  // V read (mt, ms, dt, cur): kp[mt*2+ms] + 8192 + dt*4096 + cur*16384
  // (identical index form since phys_K=(ks*2+hl)^sz, phys_V=((mt*2+ms)*2+hl)^sz,
  //  and swzr has period 32 so mt/dt deltas are the constants 4096/4096 bytes)
  const char* KVc = (const char*)KV;
  const int sz = swzr(lane31);
  const char* kp[4];
#pragma unroll
  for (int ks = 0; ks < 4; ++ks)
    kp[ks] = KVc + g * 32768 + lane31 * 128 + (((ks * 2 + hl) ^ sz) * 16);

  // ---- running global stage pointers (advance by constants per iter) ----
  const int srow0 = nw * 8 + r8;
  const int cswz = (scb ^ swzr(srow0)) * 16;  // same for row and row+32
  const char* kgp0 = (const char*)Kg + (size_t)srow0 * 128 + cswz;
  const char* kgp1 = kgp0 + 4096;  // row+32
  const char* vgp0 = (const char*)Vg + (size_t)srow0 * (DSTR * 2) + cswz;
  const char* vgp1 = vgp0 + (size_t)32 * DSTR * 2;  // row+32

  // ---- wave-uniform LDS stage destinations (buf0; buf1 = +8192 ushorts) ----
  unsigned short* ldsK0 = KV + KVOFF(g, 0, 0) + (nw * 8) * 64;
  unsigned short* ldsK1 = ldsK0 + 32 * 64;
  unsigned short* ldsV0 = KV + KVOFF(g, 0, 1) + (nw * 8) * 64;
  unsigned short* ldsV1 = ldsV0 + 32 * 64;

  // ---- stage K/V iter 0 into buf 0 ----
  gld16(kgp0, ldsK0);
  gld16(kgp1, ldsK1);
  gld16(vgp0, ldsV0);
  gld16(vgp1, ldsV1);
  kgp0 += 8192; kgp1 += 8192; vgp0 += 128; vgp1 += 128;
  __syncthreads();

  f32x16 O[2];  // [dt]; col = d = dt*32+lane31, regs = n-rows
  O[0] = zero16();
  O[1] = zero16();
  f32x2 ls2 = {0.f, 0.f};

#define VREAD(C, DT, CUR) (*(const bf16x8*)(kp[C] + 8192 + (DT)*4096 + (CUR)*16384))

#define PVT(MT, CUR, A0, A1)                                                     \
  {                                                                              \
    bf16x8 v00 = VREAD((MT)*2 + 0, 0, CUR);                                      \
    bf16x8 v01 = VREAD((MT)*2 + 0, 1, CUR);                                      \
    bf16x8 v10 = VREAD((MT)*2 + 1, 0, CUR);                                      \
    bf16x8 v11 = VREAD((MT)*2 + 1, 1, CUR);                                      \
    O[0] = __builtin_amdgcn_mfma_f32_32x32x16_bf16(A0, v00, O[0], 0, 0, 0);      \
    O[1] = __builtin_amdgcn_mfma_f32_32x32x16_bf16(A0, v01, O[1], 0, 0, 0);      \
    O[0] = __builtin_amdgcn_mfma_f32_32x32x16_bf16(A1, v10, O[0], 0, 0, 0);      \
    O[1] = __builtin_amdgcn_mfma_f32_32x32x16_bf16(A1, v11, O[1], 0, 0, 0);      \
  }

#define ATTN_ITER(CUR, DO_STAGE)                                                 \
  {                                                                              \
    if (DO_STAGE) {                                                              \
      gld16(kgp0, ldsK0 + (1 - (CUR)) * 8192);                                   \
      gld16(kgp1, ldsK1 + (1 - (CUR)) * 8192);                                   \
      gld16(vgp0, ldsV0 + (1 - (CUR)) * 8192);                                   \
      gld16(vgp1, ldsV1 + (1 - (CUR)) * 8192);                                   \
      kgp0 += 8192; kgp1 += 8192; vgp0 += 128; vgp1 += 128;                      \
    }                                                                            \
    {                                                                            \
      __builtin_amdgcn_s_setprio(1);                                             \
      f32x16 St = qk4(kp, (CUR)*16384, bQ);                                      \
      __builtin_amdgcn_s_setprio(0);                                             \
      bf16x8 a0, a1;                                                             \
      exppack(St, ls2, a0, a1);                                                  \
      __builtin_amdgcn_s_setprio(1);                                             \
      PVT(0, CUR, a0, a1);                                                       \
      __builtin_amdgcn_s_setprio(0);                                             \
    }                                                                            \
    {                                                                            \
      __builtin_amdgcn_s_setprio(1);                                             \
      f32x16 St = qk4(kp, 4096 + (CUR)*16384, bQ);                               \
      __builtin_amdgcn_s_setprio(0);                                             \
      bf16x8 a0, a1;                                                             \
      exppack(St, ls2, a0, a1);                                                  \
      __builtin_amdgcn_s_setprio(1);                                             \
      PVT(1, CUR, a0, a1);                                                       \
      __builtin_amdgcn_s_setprio(0);                                             \
    }                                                                            \
    __syncthreads();                                                             \
  }

  for (int j = 0; j < 8; ++j) {
    ATTN_ITER(0, 1);
    ATTN_ITER(1, (j < 7));
  }

#undef ATTN_ITER
#undef PVT
#undef VREAD

  // ---- epilogue: combine the two m-groups in LDS, normalize, store ----
  float lsum = ls2[0] + ls2[1];
  lsum += __shfl_xor(lsum, 32, 64);
  if (hl == 0) lsumLDS[g * 128 + nw * 32 + lane31] = lsum;
  if (g == 1) {
#pragma unroll
    for (int dt = 0; dt < 2; ++dt)
#pragma unroll
      for (int r = 0; r < 16; ++r) {
        int nl = nw * 32 + (r & 3) + 8 * (r >> 2) + 4 * hl;
        Oex[nl * 64 + dt * 32 + lane31] = O[dt][r];
      }
  }
  __syncthreads();
  if (g == 0) {
    const size_t xb = (size_t)b * ((size_t)NSEQ * CCH);
#pragma unroll
    for (int rq = 0; rq < 4; ++rq) {
      int nlb = nw * 32 + rq * 8 + 4 * hl;
      float4 l0 = *(const float4*)&lsumLDS[nlb];
      float4 l1 = *(const float4*)&lsumLDS[128 + nlb];
      float inv0 = 1.0f / (l0.x + l1.x);
      float inv1 = 1.0f / (l0.y + l1.y);
      float inv2 = 1.0f / (l0.z + l1.z);
      float inv3 = 1.0f / (l0.w + l1.w);
#pragma unroll
      for (int dt = 0; dt < 2; ++dt) {
        int d = dt * 32 + lane31;
#pragma unroll
        for (int rr = 0; rr < 4; ++rr) {
          int r = rq * 4 + rr;
          float val = O[dt][r] + Oex[(nlb + rr) * 64 + d];
          float inv = (rr == 0) ? inv0 : (rr == 1) ? inv1 : (rr == 2) ? inv2 : inv3;
          int n = n0 + nlb + rr;
          xt[xb + (size_t)n * CCH + hh * 64 + d] = f2bf(val * inv);
        }
      }
    }
  }
#undef KVOFF
}

// ---------------- merge GEMM: 64x64 tiles, grid 1024 (4 blocks/CU), dbuf ----------------
__global__ __launch_bounds__(256) void merge5(const unsigned short* __restrict__ Wp,
                                              const unsigned short* __restrict__ xt,
                                              const float* __restrict__ bias,
                                              float* __restrict__ out) {
  __shared__ unsigned short At[2][64 * 64];  // 2 x 8 KB
  __shared__ unsigned short Bt[2][64 * 64];  // 2 x 8 KB
  const int tid = threadIdx.x;
  const int w = tid >> 6, lane = tid & 63;
  const int quad = lane >> 4, l16 = lane & 15;
  const int wx = w & 1, wy = w >> 1;  // n half / o half
  const int n0 = blockIdx.x * 64, o0 = blockIdx.y * 64, b = blockIdx.z;
  const int srow = w * 8 + (lane >> 3), scb = lane & 7;
  const unsigned short* Bbase = xt + (size_t)b * ((size_t)NSEQ * CCH);

  f32x4 acc[2][2];  // [ot][nt]
#pragma unroll
  for (int ot = 0; ot < 2; ++ot)
#pragma unroll
    for (int nt = 0; nt < 2; ++nt) acc[ot][nt] = (f32x4){0.f, 0.f, 0.f, 0.f};

  // stage c0=0 into buf 0 (64 rows each of A and B; 8 waves-worth: 4 waves x 2)
#pragma unroll
  for (int i = 0; i < 2; ++i) {
    int row = i * 32 + srow;
    int cbl = scb ^ (row & 7);
    gld16(Wp + (size_t)(o0 + row) * CCH + cbl * 8, &At[0][(i * 32 + w * 8) * 64]);
    gld16(Bbase + (size_t)(n0 + row) * CCH + cbl * 8, &Bt[0][(i * 32 + w * 8) * 64]);
  }
  __syncthreads();

  for (int it = 0; it < 16; ++it) {
    const int cur = it & 1;
    if (it < 15) {
      const int nxt = cur ^ 1;
      const int c0 = (it + 1) * 64;
#pragma unroll
      for (int i = 0; i < 2; ++i) {
        int row = i * 32 + srow;
        int cbl = scb ^ (row & 7);
        gld16(Wp + (size_t)(o0 + row) * CCH + c0 + cbl * 8, &At[nxt][(i * 32 + w * 8) * 64]);
        gld16(Bbase + (size_t)(n0 + row) * CCH + c0 + cbl * 8, &Bt[nxt][(i * 32 + w * 8) * 64]);
      }
    }
#pragma unroll
    for (int ks = 0; ks < 2; ++ks) {
      int phys = ((ks * 4 + quad) ^ (l16 & 7)) * 8;
      bf16x8 aW[2], bX[2];
#pragma unroll
      for (int ot = 0; ot < 2; ++ot)
        aW[ot] = *(const bf16x8*)&At[cur][(wy * 32 + ot * 16 + l16) * 64 + phys];
#pragma unroll
      for (int nt = 0; nt < 2; ++nt)
        bX[nt] = *(const bf16x8*)&Bt[cur][(wx * 32 + nt * 16 + l16) * 64 + phys];
#pragma unroll
      for (int ot = 0; ot < 2; ++ot)
#pragma unroll
        for (int nt = 0; nt < 2; ++nt)
          acc[ot][nt] =
              __builtin_amdgcn_mfma_f32_16x16x32_bf16(aW[ot], bX[nt], acc[ot][nt], 0, 0, 0);
    }
    __syncthreads();
  }

#pragma unroll
  for (int ot = 0; ot < 2; ++ot) {
#pragma unroll
    for (int r = 0; r < 4; ++r) {
      int o = o0 + wy * 32 + ot * 16 + quad * 4 + r;
      float br = bias[o];
#pragma unroll
      for (int nt = 0; nt < 2; ++nt)
        out[(size_t)b * ((size_t)CCH * NSEQ) + (size_t)o * NSEQ + n0 + wx * 32 + nt * 16 + l16] =
            acc[ot][nt][r] + br;
    }
  }
}

extern "C" void kernel_launch(void* const* d_in, const int* in_sizes, int n_in,
                              void* d_out, int out_size, void* d_ws, size_t ws_size,
                              hipStream_t stream) {
  const float* q = (const float*)d_in[0];
  const float* k = (const float*)d_in[1];
  const float* v = (const float*)d_in[2];
  const float* W = (const float*)d_in[3];
  const float* bias = (const float*)d_in[4];
  float* out = (float*)d_out;

  // ws layout (ushort units): Wp 1Mi | xt 4Mi | Qt 4Mi | Kt 4Mi | Vb 4Mi = 34 MiB
  unsigned short* Wp = (unsigned short*)d_ws;
  unsigned short* xt = Wp + (1u << 20);
  unsigned short* Qt = xt + (4u << 20);
  unsigned short* Kt = Qt + (4u << 20);
  unsigned short* Vb = Kt + (4u << 20);

  hipLaunchKernelGGL(prep_all, dim3(7168), dim3(256), 0, stream, W, v, q, k, Wp, Vb, Qt, Kt);
  hipLaunchKernelGGL(attn8, dim3(NSEQ / 128, H, BATCH), dim3(512), 0, stream, Qt, Kt, Vb, xt);
  hipLaunchKernelGGL(merge5, dim3(NSEQ / 64, CCH / 64, BATCH), dim3(256), 0, stream,
                     Wp, xt, bias, out);
}

// Round 3
// 162.647 us; speedup vs baseline: 1.0307x; 1.0307x over previous
//
#include <hip/hip_runtime.h>

// MHSA fused pipeline v9, MI355X gfx950.
// B=2, N=2048, C=1024, H=16, dim=64.
//
// v9 (from v8): barrier-free attention. Three instruction-level nulls at a
// pinned 51.5us (bank-conflicts->0, MFMA/VALU reorder, VALU -7pt) prove the
// wall is the barrier-lockstep + LDS convoy, not issue bandwidth. So: prep
// now emits fragment-major layouts (KA[mb][sub][m31][8], VB[kb][d][8]) so
// every MFMA fragment is a fully-coalesced 1KB-contiguous wave load directly
// global->VGPR. Attention has NO K/V LDS, NO swizzle, NO main-loop barrier
// (one drift-control barrier every 8 chunks keeps the 4 waves sharing a K/V
// stream L1-resident). L1 (32KB/CU) serves the 4-way intra-group fragment
// reuse; L2 traffic unchanged vs v8 staging. LDS keeps only the epilogue
// combine (33KB). 1-chunk K prefetch; setprio around MFMA clusters.

#define H 16
#define NSEQ 2048
#define CCH 1024
#define BATCH 2
#define DSTR (H * NSEQ)  // 32768

typedef __attribute__((ext_vector_type(8))) short bf16x8;
typedef __attribute__((ext_vector_type(2))) float f32x2;
typedef __attribute__((ext_vector_type(4))) float f32x4;
typedef __attribute__((ext_vector_type(16))) float f32x16;
typedef __attribute__((ext_vector_type(4))) unsigned int uint32x4;

__device__ __forceinline__ unsigned short f2bf(float x) {
  unsigned int u = __builtin_bit_cast(unsigned int, x);
  u += 0x7FFFu + ((u >> 16) & 1u);  // RNE
  return (unsigned short)(u >> 16);
}

__device__ __forceinline__ unsigned int pack2bf(float a, float b) {
#if __has_builtin(__builtin_amdgcn_cvt_pk_bf16_f32)
  typedef __attribute__((ext_vector_type(2))) __bf16 bf16x2_t;
  bf16x2_t r = __builtin_amdgcn_cvt_pk_bf16_f32(a, b);
  return __builtin_bit_cast(unsigned int, r);
#else
  unsigned int ua = __builtin_bit_cast(unsigned int, a);
  unsigned int ub = __builtin_bit_cast(unsigned int, b);
  ua += 0x7FFFu + ((ua >> 16) & 1u);
  ub += 0x7FFFu + ((ub >> 16) & 1u);
  return __builtin_amdgcn_perm(ub, ua, 0x07060302u);
#endif
}

__device__ __forceinline__ float fast_exp2(float x) {
#if __has_builtin(__builtin_amdgcn_exp2f)
  return __builtin_amdgcn_exp2f(x);
#else
  return exp2f(x);
#endif
}

__device__ __forceinline__ void permswap32(unsigned int& a, unsigned int& b) {
#if __has_builtin(__builtin_amdgcn_permlane32_swap)
  typedef __attribute__((ext_vector_type(2))) unsigned int uint2v;
  uint2v r = __builtin_amdgcn_permlane32_swap(a, b, false, false);
  a = r[0];
  b = r[1];
#else
  unsigned int ax = (unsigned int)__shfl_xor((int)a, 32, 64);
  unsigned int bx = (unsigned int)__shfl_xor((int)b, 32, 64);
  bool lo = (threadIdx.x & 63) < 32;
  unsigned int na = lo ? a : bx;
  unsigned int nb = lo ? ax : b;
  a = na;
  b = nb;
#endif
}

__device__ __forceinline__ void gld16(const void* g, void* l) {
  __builtin_amdgcn_global_load_lds(
      (const __attribute__((address_space(1))) unsigned int*)g,
      (__attribute__((address_space(3))) unsigned int*)l, 16, 0, 0);
}

__device__ __forceinline__ f32x16 zero16() {
  f32x16 v;
#pragma unroll
  for (int i = 0; i < 16; ++i) v[i] = 0.f;
  return v;
}

// ---------------- fused prep: W permute | V->VB frag-major | Q transpose | K->KA ----------------
// grid 5120: [0,1024) W | [1024,3072) VB | [3072,5120) Q/K transpose.
__global__ __launch_bounds__(256) void prep_all(const float* __restrict__ W,
                                                const float* __restrict__ v,
                                                const float* __restrict__ q,
                                                const float* __restrict__ k,
                                                unsigned short* __restrict__ Wp,
                                                unsigned short* __restrict__ VB,
                                                unsigned short* __restrict__ Qt,
                                                unsigned short* __restrict__ KA) {
  __shared__ unsigned short T[64][72];
  __shared__ unsigned short VL[256 * 8];  // 4 KB bounce for VB writes
  const int bid = blockIdx.x, tid = threadIdx.x;

  if (bid < 1024) {
    const int o = bid;
    const int cp = tid * 4;
    const int hh = cp >> 6;
    const int d0 = cp & 63;
    const float* Wr = W + (size_t)o * CCH;
    ushort4 ov;
    ov.x = f2bf(Wr[(d0 + 0) * H + hh]);
    ov.y = f2bf(Wr[(d0 + 1) * H + hh]);
    ov.z = f2bf(Wr[(d0 + 2) * H + hh]);
    ov.w = f2bf(Wr[(d0 + 3) * H + hh]);
    *(ushort4*)&Wp[(size_t)o * CCH + cp] = ov;
  } else if (bid < 3072) {
    // VB[bh][kb=256][d=64][mi=8]: chunk (kb,d) = bf16(V[b][d][h][n=kb*8..+8]).
    // Block covers (bh, kbb): n-range [kbb*32, kbb*32+32).
    const int vb = bid - 1024;
    const int bh = vb >> 6, kbb = vb & 63;
    const int bb = bh >> 4, hhh = bh & 15;
    // read phase: coalesced along n
    const int d = tid >> 2, nq = (tid & 3) * 8;
    const float* srcv =
        v + (size_t)bb * (CCH * NSEQ) + (size_t)d * DSTR + hhh * NSEQ + kbb * 32 + nq;
    float4 x0 = *(const float4*)srcv;
    float4 x1 = *(const float4*)(srcv + 4);
    unsigned short* Lc = &VL[tid * 8];
    Lc[0] = f2bf(x0.x); Lc[1] = f2bf(x0.y); Lc[2] = f2bf(x0.z); Lc[3] = f2bf(x0.w);
    Lc[4] = f2bf(x1.x); Lc[5] = f2bf(x1.y); Lc[6] = f2bf(x1.z); Lc[7] = f2bf(x1.w);
    __syncthreads();
    // write phase: coalesced along d (1KB contiguous per kb)
    const int kb_lo = tid >> 6, d2 = tid & 63;
    *(bf16x8*)(VB + (size_t)bh * 131072 + (size_t)(kbb * 4 + kb_lo) * 512 + d2 * 8) =
        *(const bf16x8*)&VL[(d2 * 4 + kb_lo) * 8];
  } else {
    const int lbid = bid - 3072;
    const int n0 = (lbid & 31) * 64;
    const int hh = (lbid >> 5) & 15;
    const int zz = lbid >> 9;
    const int b = zz >> 1, t = zz & 1;
    const float* src = t ? k : q;
    // Q scale: 1/sqrt(2048) * log2(e)  (softmax exp -> exp2)
    const float scl = t ? 1.0f : (0.022097086912079608f * 1.4426950408889634f);
    const size_t base = (size_t)b * (CCH * NSEQ) + (size_t)hh * NSEQ;
#pragma unroll
    for (int it = 0; it < 4; ++it) {
      int i4 = it * 256 + tid;
      int d = i4 >> 4;
      int nn = (i4 & 15) << 2;
      float4 val = *(const float4*)(src + base + (size_t)d * DSTR + n0 + nn);
      T[nn + 0][d] = f2bf(val.x * scl);
      T[nn + 1][d] = f2bf(val.y * scl);
      T[nn + 2][d] = f2bf(val.z * scl);
      T[nn + 3][d] = f2bf(val.w * scl);
    }
    __syncthreads();
    if (t == 0) {
      // Qt: plain [n][64 d] rows
      const size_t obase = ((size_t)(b * H + hh) * NSEQ + n0) * 64;
#pragma unroll
      for (int it = 0; it < 2; ++it) {
        int idx = it * 256 + tid;
        int row = idx >> 3, cb = idx & 7;
        *(bf16x8*)(Qt + obase + (size_t)row * 64 + cb * 8) = *(const bf16x8*)&T[row][cb * 8];
      }
    } else {
      // KA[bh][mb=64][sub=8][m31=32][8]: chunk = K[m=mb*32+m31][d=sub*8..+8]
      const size_t obase = (size_t)(b * H + hh) * 131072 + (size_t)(n0 >> 5) * 2048;
#pragma unroll
      for (int it = 0; it < 2; ++it) {
        int idx = it * 256 + tid;
        int nl = idx >> 3, sub = idx & 7;
        *(bf16x8*)(KA + obase + (size_t)(nl >> 5) * 2048 + sub * 256 + (nl & 31) * 8) =
            *(const bf16x8*)&T[nl][sub * 8];
      }
    }
  }
}

// ---- attn helpers ----

// P = exp2(St), pack to bf16, C-layout -> A-layout in-register.
__device__ __forceinline__ void exppack(const f32x16& St, f32x2& ls2, bf16x8& a0, bf16x8& a1) {
  unsigned int pd[8];
#pragma unroll
  for (int t = 0; t < 8; ++t) {
    float e0 = fast_exp2(St[2 * t]);
    float e1 = fast_exp2(St[2 * t + 1]);
    ls2 += (f32x2){e0, e1};
    pd[t] = pack2bf(e0, e1);
  }
  unsigned int s0[4] = {pd[0], pd[1], pd[2], pd[3]};
  unsigned int s1[4] = {pd[4], pd[5], pd[6], pd[7]};
  permswap32(s0[0], s0[2]);
  permswap32(s0[1], s0[3]);
  permswap32(s1[0], s1[2]);
  permswap32(s1[1], s1[3]);
  a0 = __builtin_bit_cast(bf16x8, (uint32x4){s0[0], s0[1], s0[2], s0[3]});
  a1 = __builtin_bit_cast(bf16x8, (uint32x4){s1[0], s1[1], s1[2], s1[3]});
}

// ---------------- attention v9 ----------------
// grid (16,16,2) = 512 blocks (2/CU), block 512 = 8 waves: g = m-group
// (2 x 1024 m), nw = n-wave (4 x 32 rows). All fragments load direct
// global->VGPR from frag-major KA/VB; no K/V LDS, no main-loop barriers.
__global__ __launch_bounds__(512, 4) void attn9(const unsigned short* __restrict__ Qt,
                                                const unsigned short* __restrict__ KA,
                                                const unsigned short* __restrict__ VB,
                                                unsigned short* __restrict__ xt) {
  __shared__ __align__(16) float eplds[128 * 64 + 256];  // Oex 32KB + lsum 1KB
  float* Oex = eplds;
  float* lsumLDS = eplds + 8192;

  const int tid = threadIdx.x;
  const int w = tid >> 6, lane = tid & 63;
  const int lane31 = lane & 31, hl = lane >> 5;
  const int g = w >> 2, nw = w & 3;
  const int n0 = blockIdx.x * 128;
  const int hh = blockIdx.y, b = blockIdx.z;
  const int bh = b * H + hh;

  // ---- loop-invariant Q B-fragments, direct from Qt: B[col=n=lane31][k=d] ----
  bf16x8 bQ[4];
  const unsigned short* Qb = Qt + ((size_t)bh * NSEQ + n0 + nw * 32 + lane31) * 64;
#pragma unroll
  for (int ks = 0; ks < 4; ++ks) bQ[ks] = *(const bf16x8*)(Qb + (ks * 2 + hl) * 8);

  // per-lane fragment pointers (advance by 2048 elems per 32-m chunk)
  const unsigned short* kp = KA + (size_t)bh * 131072 + g * 65536 + hl * 256 + lane31 * 8;
  const unsigned short* vp = VB + (size_t)bh * 131072 + g * 65536 + hl * 512 + lane31 * 8;

  f32x16 O[2];  // [dt]; col = d = dt*32+lane31, regs = n-rows
  O[0] = zero16();
  O[1] = zero16();
  f32x2 ls2 = {0.f, 0.f};

#define LOADK(R0, R1, R2, R3, C)                      \
  {                                                   \
    const unsigned short* kc_ = kp + (C)*2048;        \
    R0 = *(const bf16x8*)(kc_);                       \
    R1 = *(const bf16x8*)(kc_ + 512);                 \
    R2 = *(const bf16x8*)(kc_ + 1024);                \
    R3 = *(const bf16x8*)(kc_ + 1536);                \
  }

#define CHUNK(K0, K1, K2, K3, C)                                                \
  {                                                                             \
    __builtin_amdgcn_s_setprio(1);                                              \
    f32x16 St = zero16();                                                       \
    St = __builtin_amdgcn_mfma_f32_32x32x16_bf16(K0, bQ[0], St, 0, 0, 0);       \
    St = __builtin_amdgcn_mfma_f32_32x32x16_bf16(K1, bQ[1], St, 0, 0, 0);       \
    St = __builtin_amdgcn_mfma_f32_32x32x16_bf16(K2, bQ[2], St, 0, 0, 0);       \
    St = __builtin_amdgcn_mfma_f32_32x32x16_bf16(K3, bQ[3], St, 0, 0, 0);       \
    __builtin_amdgcn_s_setprio(0);                                              \
    bf16x8 a0, a1;                                                              \
    exppack(St, ls2, a0, a1);                                                   \
    const unsigned short* vc_ = vp + (C)*2048;                                  \
    bf16x8 v00 = *(const bf16x8*)(vc_);                                         \
    bf16x8 v01 = *(const bf16x8*)(vc_ + 256);                                   \
    bf16x8 v10 = *(const bf16x8*)(vc_ + 1024);                                  \
    bf16x8 v11 = *(const bf16x8*)(vc_ + 1280);                                  \
    __builtin_amdgcn_s_setprio(1);                                              \
    O[0] = __builtin_amdgcn_mfma_f32_32x32x16_bf16(a0, v00, O[0], 0, 0, 0);     \
    O[1] = __builtin_amdgcn_mfma_f32_32x32x16_bf16(a0, v01, O[1], 0, 0, 0);     \
    O[0] = __builtin_amdgcn_mfma_f32_32x32x16_bf16(a1, v10, O[0], 0, 0, 0);     \
    O[1] = __builtin_amdgcn_mfma_f32_32x32x16_bf16(a1, v11, O[1], 0, 0, 0);     \
    __builtin_amdgcn_s_setprio(0);                                              \
  }

  bf16x8 kA0, kA1, kA2, kA3, kB0, kB1, kB2, kB3;
  LOADK(kA0, kA1, kA2, kA3, 0);
  for (int j = 0; j < 16; ++j) {
    LOADK(kB0, kB1, kB2, kB3, 2 * j + 1);  // prefetch next chunk's K
    CHUNK(kA0, kA1, kA2, kA3, 2 * j);
    LOADK(kA0, kA1, kA2, kA3, 2 * j + 2);  // j=15 overruns into VB[0..] (ws, harmless)
    CHUNK(kB0, kB1, kB2, kB3, 2 * j + 1);
    if ((j & 3) == 3) __syncthreads();  // drift control: keep group L1-resident
  }
#undef CHUNK
#undef LOADK

  // ---- epilogue: combine the two m-groups in LDS, normalize, store ----
  float lsum = ls2[0] + ls2[1];
  lsum += __shfl_xor(lsum, 32, 64);
  if (hl == 0) lsumLDS[g * 128 + nw * 32 + lane31] = lsum;
  if (g == 1) {
#pragma unroll
    for (int dt = 0; dt < 2; ++dt)
#pragma unroll
      for (int r = 0; r < 16; ++r) {
        int nl = nw * 32 + (r & 3) + 8 * (r >> 2) + 4 * hl;
        Oex[nl * 64 + dt * 32 + lane31] = O[dt][r];
      }
  }
  __syncthreads();
  if (g == 0) {
    const size_t xb = (size_t)b * ((size_t)NSEQ * CCH);
#pragma unroll
    for (int rq = 0; rq < 4; ++rq) {
      int nlb = nw * 32 + rq * 8 + 4 * hl;
      float4 l0 = *(const float4*)&lsumLDS[nlb];
      float4 l1 = *(const float4*)&lsumLDS[128 + nlb];
      float inv0 = 1.0f / (l0.x + l1.x);
      float inv1 = 1.0f / (l0.y + l1.y);
      float inv2 = 1.0f / (l0.z + l1.z);
      float inv3 = 1.0f / (l0.w + l1.w);
#pragma unroll
      for (int dt = 0; dt < 2; ++dt) {
        int d = dt * 32 + lane31;
#pragma unroll
        for (int rr = 0; rr < 4; ++rr) {
          int r = rq * 4 + rr;
          float val = O[dt][r] + Oex[(nlb + rr) * 64 + d];
          float inv = (rr == 0) ? inv0 : (rr == 1) ? inv1 : (rr == 2) ? inv2 : inv3;
          int n = n0 + nlb + rr;
          xt[xb + (size_t)n * CCH + hh * 64 + d] = f2bf(val * inv);
        }
      }
    }
  }
}

// ---------------- merge GEMM: 64x64 tiles, grid 1024 (4 blocks/CU), dbuf ----------------
__global__ __launch_bounds__(256) void merge5(const unsigned short* __restrict__ Wp,
                                              const unsigned short* __restrict__ xt,
                                              const float* __restrict__ bias,
                                              float* __restrict__ out) {
  __shared__ unsigned short At[2][64 * 64];  // 2 x 8 KB
  __shared__ unsigned short Bt[2][64 * 64];  // 2 x 8 KB
  const int tid = threadIdx.x;
  const int w = tid >> 6, lane = tid & 63;
  const int quad = lane >> 4, l16 = lane & 15;
  const int wx = w & 1, wy = w >> 1;  // n half / o half
  const int n0 = blockIdx.x * 64, o0 = blockIdx.y * 64, b = blockIdx.z;
  const int srow = w * 8 + (lane >> 3), scb = lane & 7;
  const unsigned short* Bbase = xt + (size_t)b * ((size_t)NSEQ * CCH);

  f32x4 acc[2][2];  // [ot][nt]
#pragma unroll
  for (int ot = 0; ot < 2; ++ot)
#pragma unroll
    for (int nt = 0; nt < 2; ++nt) acc[ot][nt] = (f32x4){0.f, 0.f, 0.f, 0.f};

  // stage c0=0 into buf 0 (64 rows each of A and B; 8 waves-worth: 4 waves x 2)
#pragma unroll
  for (int i = 0; i < 2; ++i) {
    int row = i * 32 + srow;
    int cbl = scb ^ (row & 7);
    gld16(Wp + (size_t)(o0 + row) * CCH + cbl * 8, &At[0][(i * 32 + w * 8) * 64]);
    gld16(Bbase + (size_t)(n0 + row) * CCH + cbl * 8, &Bt[0][(i * 32 + w * 8) * 64]);
  }
  __syncthreads();

  for (int it = 0; it < 16; ++it) {
    const int cur = it & 1;
    if (it < 15) {
      const int nxt = cur ^ 1;
      const int c0 = (it + 1) * 64;
#pragma unroll
      for (int i = 0; i < 2; ++i) {
        int row = i * 32 + srow;
        int cbl = scb ^ (row & 7);
        gld16(Wp + (size_t)(o0 + row) * CCH + c0 + cbl * 8, &At[nxt][(i * 32 + w * 8) * 64]);
        gld16(Bbase + (size_t)(n0 + row) * CCH + c0 + cbl * 8, &Bt[nxt][(i * 32 + w * 8) * 64]);
      }
    }
#pragma unroll
    for (int ks = 0; ks < 2; ++ks) {
      int phys = ((ks * 4 + quad) ^ (l16 & 7)) * 8;
      bf16x8 aW[2], bX[2];
#pragma unroll
      for (int ot = 0; ot < 2; ++ot)
        aW[ot] = *(const bf16x8*)&At[cur][(wy * 32 + ot * 16 + l16) * 64 + phys];
#pragma unroll
      for (int nt = 0; nt < 2; ++nt)
        bX[nt] = *(const bf16x8*)&Bt[cur][(wx * 32 + nt * 16 + l16) * 64 + phys];
#pragma unroll
      for (int ot = 0; ot < 2; ++ot)
#pragma unroll
        for (int nt = 0; nt < 2; ++nt)
          acc[ot][nt] =
              __builtin_amdgcn_mfma_f32_16x16x32_bf16(aW[ot], bX[nt], acc[ot][nt], 0, 0, 0);
    }
    __syncthreads();
  }

#pragma unroll
  for (int ot = 0; ot < 2; ++ot) {
#pragma unroll
    for (int r = 0; r < 4; ++r) {
      int o = o0 + wy * 32 + ot * 16 + quad * 4 + r;
      float br = bias[o];
#pragma unroll
      for (int nt = 0; nt < 2; ++nt)
        out[(size_t)b * ((size_t)CCH * NSEQ) + (size_t)o * NSEQ + n0 + wx * 32 + nt * 16 + l16] =
            acc[ot][nt][r] + br;
    }
  }
}

extern "C" void kernel_launch(void* const* d_in, const int* in_sizes, int n_in,
                              void* d_out, int out_size, void* d_ws, size_t ws_size,
                              hipStream_t stream) {
  const float* q = (const float*)d_in[0];
  const float* k = (const float*)d_in[1];
  const float* v = (const float*)d_in[2];
  const float* W = (const float*)d_in[3];
  const float* bias = (const float*)d_in[4];
  float* out = (float*)d_out;

  // ws layout (ushort units): Wp 1Mi | xt 4Mi | Qt 4Mi | KA 4Mi | VB 4Mi = 34 MiB
  unsigned short* Wp = (unsigned short*)d_ws;
  unsigned short* xt = Wp + (1u << 20);
  unsigned short* Qt = xt + (4u << 20);
  unsigned short* KA = Qt + (4u << 20);
  unsigned short* VB = KA + (4u << 20);

  hipLaunchKernelGGL(prep_all, dim3(5120), dim3(256), 0, stream, W, v, q, k, Wp, VB, Qt, KA);
  hipLaunchKernelGGL(attn9, dim3(NSEQ / 128, H, BATCH), dim3(512), 0, stream, Qt, KA, VB, xt);
  hipLaunchKernelGGL(merge5, dim3(NSEQ / 64, CCH / 64, BATCH), dim3(256), 0, stream,
                     Wp, xt, bias, out);
}